// Round 4
// baseline (256.540 us; speedup 1.0000x reference)
//
#include <hip/hip_runtime.h>

// ElasticEmbedding: out[t,:] = residual_embedding[remap[x[t]]] if x[t] is a
// residual id else pretrained_embedding[x[t]].  D = 128 floats (= 32 x 16B).
// remap table (V ints) in d_ws.  Gather: 32 lanes/token, 16B/lane,
// 8 CONSECUTIVE tokens per group (8 independent load chains per thread,
// wave64 covers a contiguous 8KB output span), nontemporal stores so the
// streaming 134 MB output doesn't evict the 61 MB tables from L2/L3.

#define BLOCK 256
#define UNROLL 8

typedef __attribute__((ext_vector_type(4))) float f4;

__global__ void fill_remap_kernel(int* __restrict__ remap, int V) {
    int i = blockIdx.x * blockDim.x + threadIdx.x;
    if (i < V) remap[i] = -1;
}

__global__ void scatter_remap_kernel(int* __restrict__ remap,
                                     const int* __restrict__ ridx, int R) {
    int i = blockIdx.x * blockDim.x + threadIdx.x;
    if (i < R) remap[ridx[i]] = i;
}

__global__ __launch_bounds__(BLOCK) void gather_kernel(
        const int* __restrict__ x,
        const int* __restrict__ remap,
        const f4* __restrict__ pre,   // [V, 32] 16B chunks
        const f4* __restrict__ res,   // [R, 32]
        f4* __restrict__ out,         // [n_tokens, 32]
        int n_tokens) {
    int g    = (blockIdx.x * BLOCK + threadIdx.x) >> 5;   // 32-lane group id
    int lane = threadIdx.x & 31;
    int base = g * UNROLL;                                 // first token

    const f4* src[UNROLL];
    bool ok[UNROLL];

    // Issue all id -> remap -> row-pointer chains first: 8 independent
    // dependency chains in flight per thread.
    #pragma unroll
    for (int k = 0; k < UNROLL; ++k) {
        int tok = base + k;
        ok[k] = tok < n_tokens;
        if (ok[k]) {
            int t = x[tok];           // 8 consecutive ints, L1-friendly
            int r = remap[t];
            src[k] = (r >= 0) ? res + (size_t)r * 32
                              : pre + (size_t)t * 32;
        }
    }

    f4 val[UNROLL];
    #pragma unroll
    for (int k = 0; k < UNROLL; ++k)
        if (ok[k]) val[k] = src[k][lane];   // 8 outstanding 16B loads/thread

    #pragma unroll
    for (int k = 0; k < UNROLL; ++k)
        if (ok[k])
            __builtin_nontemporal_store(val[k],
                &out[(size_t)(base + k) * 32 + lane]);  // wave64: 8KB contiguous
}

extern "C" void kernel_launch(void* const* d_in, const int* in_sizes, int n_in,
                              void* d_out, int out_size, void* d_ws, size_t ws_size,
                              hipStream_t stream) {
    const int* x    = (const int*)d_in[0];     // [B*S] token ids
    const int* ridx = (const int*)d_in[1];     // [R] sorted residual ids
    const f4*  pre  = (const f4*)d_in[2];      // [V, D/4]
    const f4*  res  = (const f4*)d_in[3];      // [R, D/4]
    f4*        out  = (f4*)d_out;

    const int n_tokens = in_sizes[0];
    const int R        = in_sizes[1];
    const int D        = in_sizes[3] / R;      // 128
    const int V        = in_sizes[2] / D;      // 100000
    (void)ws_size;

    int* remap = (int*)d_ws;                   // V ints = 400 KB scratch

    fill_remap_kernel<<<(V + 255) / 256, 256, 0, stream>>>(remap, V);
    scatter_remap_kernel<<<(R + 255) / 256, 256, 0, stream>>>(remap, ridx, R);

    int n_groups = (n_tokens + UNROLL - 1) / UNROLL;   // 32768
    int threads  = n_groups * 32;                      // 1M
    int blocks   = (threads + BLOCK - 1) / BLOCK;      // 4096
    gather_kernel<<<blocks, BLOCK, 0, stream>>>(x, remap, pre, res, out,
                                                n_tokens);
}

// Round 5
// 205.118 us; speedup vs baseline: 1.2507x; 1.2507x over previous
//
#include <hip/hip_runtime.h>

// ElasticEmbedding: out[t,:] = residual_embedding[remap[x[t]]] if x[t] is a
// residual id else pretrained_embedding[x[t]].  D = 128 floats (= 32 x 16B).
//
// R5 structure: (1) build remap in ws, (2) resolve pass collapses
// x->remap->select into ONE combined int per token (sign bit = residual),
// (3) light gather: 32 lanes/token, 16B/lane, UNROLL 2 strided, low VGPR for
// max waves (TLP beat deep per-thread MLP in R4: VGPR116/8-deep = 108us).
// NT stores keep the 134MB streaming output from evicting tables in L2/L3.

#define BLOCK 256
#define UNROLL 2

typedef __attribute__((ext_vector_type(4))) float f4;

__global__ void fill_remap_kernel(int* __restrict__ remap, int V) {
    int i = blockIdx.x * blockDim.x + threadIdx.x;
    if (i < V) remap[i] = -1;
}

__global__ void scatter_remap_kernel(int* __restrict__ remap,
                                     const int* __restrict__ ridx, int R) {
    int i = blockIdx.x * blockDim.x + threadIdx.x;
    if (i < R) remap[ridx[i]] = i;
}

// combined[t]: residual -> (0x80000000 | r), else token id t.
__global__ void resolve_kernel(const int* __restrict__ x,
                               const int* __restrict__ remap,
                               int* __restrict__ combined, int n_tokens) {
    int i = blockIdx.x * blockDim.x + threadIdx.x;
    if (i >= n_tokens) return;
    int t = x[i];
    int r = remap[t];
    combined[i] = (r >= 0) ? (int)(0x80000000u | (unsigned)r) : t;
}

__global__ __launch_bounds__(BLOCK, 8) void gather_kernel(
        const int* __restrict__ combined,
        const f4* __restrict__ pre,   // [V, 32] 16B chunks
        const f4* __restrict__ res,   // [R, 32]
        f4* __restrict__ out,         // [n_tokens, 32]
        int n_tokens, int n_groups) {
    int g    = (blockIdx.x * BLOCK + threadIdx.x) >> 5;   // 32-lane group id
    int lane = threadIdx.x & 31;

    int tok[UNROLL];
    const f4* src[UNROLL];
    bool ok[UNROLL];

    #pragma unroll
    for (int k = 0; k < UNROLL; ++k) {
        tok[k] = g + k * n_groups;
        ok[k]  = tok[k] < n_tokens;
        if (ok[k]) {
            int c = combined[tok[k]];        // broadcast, 2-deep chain now
            src[k] = (c < 0) ? res + (size_t)(c & 0x7fffffff) * 32
                             : pre + (size_t)c * 32;
        }
    }

    f4 val[UNROLL];
    #pragma unroll
    for (int k = 0; k < UNROLL; ++k)
        if (ok[k]) val[k] = src[k][lane];    // 2 outstanding 16B loads/thread

    #pragma unroll
    for (int k = 0; k < UNROLL; ++k)
        if (ok[k])
            __builtin_nontemporal_store(val[k],
                &out[(size_t)tok[k] * 32 + lane]);
}

extern "C" void kernel_launch(void* const* d_in, const int* in_sizes, int n_in,
                              void* d_out, int out_size, void* d_ws, size_t ws_size,
                              hipStream_t stream) {
    const int* x    = (const int*)d_in[0];     // [B*S] token ids
    const int* ridx = (const int*)d_in[1];     // [R] sorted residual ids
    const f4*  pre  = (const f4*)d_in[2];      // [V, D/4]
    const f4*  res  = (const f4*)d_in[3];      // [R, D/4]
    f4*        out  = (f4*)d_out;

    const int n_tokens = in_sizes[0];
    const int R        = in_sizes[1];
    const int D        = in_sizes[3] / R;      // 128
    const int V        = in_sizes[2] / D;      // 100000
    (void)ws_size;

    int* remap    = (int*)d_ws;                // V ints = 400 KB
    int* combined = remap + V;                 // n_tokens ints = 1 MB

    fill_remap_kernel<<<(V + 255) / 256, 256, 0, stream>>>(remap, V);
    scatter_remap_kernel<<<(R + 255) / 256, 256, 0, stream>>>(remap, ridx, R);
    resolve_kernel<<<(n_tokens + 255) / 256, 256, 0, stream>>>(x, remap,
                                                               combined,
                                                               n_tokens);

    int n_groups = (n_tokens + UNROLL - 1) / UNROLL;   // 131072
    int threads  = n_groups * 32;
    int blocks   = (threads + BLOCK - 1) / BLOCK;      // 16384
    gather_kernel<<<blocks, BLOCK, 0, stream>>>(combined, pre, res, out,
                                                n_tokens, n_groups);
}